// Round 7
// baseline (215.016 us; speedup 1.0000x reference)
//
#include <hip/hip_runtime.h>

// x_restored: (8192, 3, 20, 20) f32
// x_distorted: (8192, 5) f32
// w1: (128, 5), w2: (1200, 128), b2: (1200,)
// conv_w: (15, 6, 3, 3), conv_b: (15,)
// out: (8192, 5, 3, 20, 20) f32

#define NB 8192

typedef __attribute__((ext_vector_type(8))) short short8;
typedef __attribute__((ext_vector_type(4))) float floatx4;

__device__ inline unsigned short f2bf(float f) {
    unsigned int u = __float_as_uint(f);
    unsigned int r = (u + 0x7FFFu + ((u >> 16) & 1u)) >> 16;
    return (unsigned short)r;
}

// ---------------- Kernel A: h = relu(x_distorted @ w1.T) -> bf16, (B,128) ----------------
__global__ __launch_bounds__(256) void mlp1_kernel(const float* __restrict__ xdist,
                                                   const float* __restrict__ w1,
                                                   unsigned short* __restrict__ hb) {
    int gid = blockIdx.x * 256 + threadIdx.x;
    int b = gid >> 7, j = gid & 127;
    const float* xr = xdist + b * 5;
    const float* wr = w1 + j * 5;
    float s = xr[0] * wr[0];
    s = fmaf(xr[1], wr[1], s);
    s = fmaf(xr[2], wr[2], s);
    s = fmaf(xr[3], wr[3], s);
    s = fmaf(xr[4], wr[4], s);
    hb[gid] = f2bf(fmaxf(s, 0.0f));
}

// ---------------- cast w2 -> bf16 ----------------
__global__ __launch_bounds__(256) void castw2_kernel(const float* __restrict__ w2,
                                                     unsigned short* __restrict__ w2b) {
    int i = blockIdx.x * 256 + threadIdx.x;   // 1200*128 = 153600 exactly
    w2b[i] = f2bf(w2[i]);
}

// ---------------- Kernel B: xd = h @ w2.T + b2 via bf16 MFMA ----------------
__global__ __launch_bounds__(256) void mlp2_mfma(const unsigned short* __restrict__ hb,
                                                 const unsigned short* __restrict__ w2b,
                                                 const float* __restrict__ b2,
                                                 float* __restrict__ xd) {
    const int tid = threadIdx.x;
    const int lane = tid & 63, wv = tid >> 6;
    const int tile = blockIdx.x * 4 + wv;          // 0..3199
    const int mt = tile / 25, nt = tile - mt * 25;
    const int rsel = lane & 15, kg = lane >> 4;

    short8 a[4][4], bfr[3][4];
    #pragma unroll
    for (int mi = 0; mi < 4; ++mi) {
        const unsigned short* ap = hb + (size_t)(mt * 64 + mi * 16 + rsel) * 128 + kg * 8;
        #pragma unroll
        for (int ks = 0; ks < 4; ++ks) a[mi][ks] = *(const short8*)(ap + ks * 32);
    }
    #pragma unroll
    for (int ni = 0; ni < 3; ++ni) {
        const unsigned short* bp = w2b + (size_t)(nt * 48 + ni * 16 + rsel) * 128 + kg * 8;
        #pragma unroll
        for (int ks = 0; ks < 4; ++ks) bfr[ni][ks] = *(const short8*)(bp + ks * 32);
    }
    floatx4 acc[4][3];
    #pragma unroll
    for (int mi = 0; mi < 4; ++mi)
        #pragma unroll
        for (int ni = 0; ni < 3; ++ni)
            acc[mi][ni] = (floatx4){0.f, 0.f, 0.f, 0.f};

    #pragma unroll
    for (int ks = 0; ks < 4; ++ks)
        #pragma unroll
        for (int mi = 0; mi < 4; ++mi)
            #pragma unroll
            for (int ni = 0; ni < 3; ++ni)
                acc[mi][ni] = __builtin_amdgcn_mfma_f32_16x16x32_bf16(
                    a[mi][ks], bfr[ni][ks], acc[mi][ni], 0, 0, 0);

    #pragma unroll
    for (int ni = 0; ni < 3; ++ni) {
        float bias = b2[nt * 48 + ni * 16 + rsel];
        #pragma unroll
        for (int mi = 0; mi < 4; ++mi) {
            #pragma unroll
            for (int r = 0; r < 4; ++r) {
                int m = mt * 64 + mi * 16 + kg * 4 + r;
                xd[(size_t)m * 1200 + nt * 48 + ni * 16 + rsel] = acc[mi][ni][r] + bias;
            }
        }
    }
}

#define GIDX(i, j) ((i) * 5 - (i) * ((i) - 1) / 2 + ((j) - (i)))
#define GF(i, j) Gm[((i) <= (j)) ? GIDX(i, j) : GIDX(j, i)]

#define XS 26            // xpad row stride (floats): (20*r2+4*xc) spreads all bank groups
#define XP (22 * XS)     // plane stride = 572 floats

// ---------------- Kernel C: conv(6->15) + Gram-space GS, 5 waves / sample ----------------
// Wave w owns output channels 3w..3w+2 (wave-uniform -> conv weights/bias via SGPR
// s_loads from global, zero LDS traffic). Lane l<50: rows 2*(l/5), 2*(l/5)+1, col quad
// 4*(l%5); 24 window floats per input plane serve 2x4 outputs x 3 channels. Conv result
// staged in LDS wl[15][404]; Gram + combine use stride-100 SCALAR reads (consecutive
// lane addresses -> conflict-free, fixes R6's 8-way float4-quad conflicts).
__global__ __launch_bounds__(320) void conv_gs_kernel(const float* __restrict__ xd,
                                                      const float* __restrict__ xres,
                                                      const float* __restrict__ cw,
                                                      const float* __restrict__ cb,
                                                      float* __restrict__ out) {
    const int b = blockIdx.x;
    const int tid = threadIdx.x;  // 0..319
    const int lane = tid & 63;
    const int wv = __builtin_amdgcn_readfirstlane(tid >> 6);  // 0..4, wave-uniform
    __shared__ __align__(16) float xpad[6 * XP];   // 3432 floats, zero-padded planes
    __shared__ __align__(16) float wl[15 * 404];   // conv output, [o][pos] stride 404
    __shared__ float gred[5][16];

    // zero xpad (858 float4)
    float4* xf4 = (float4*)xpad;
    #pragma unroll
    for (int i = 0; i < 3; ++i) {
        int idx = tid + i * 320;
        if (idx < 858) xf4[idx] = make_float4(0.f, 0.f, 0.f, 0.f);
    }
    __syncthreads();

    // fill interior: 600 float4 (ch 0-2 = xd, 3-5 = xres); rows of 20 are float4-clean
    const float* src0 = xd + (size_t)b * 1200;
    const float* src1 = xres + (size_t)b * 1200;
    #pragma unroll
    for (int i = 0; i < 2; ++i) {
        int j = tid + i * 320;
        if (j < 600) {
            float4 v = (j < 300) ? ((const float4*)src0)[j] : ((const float4*)src1)[j - 300];
            int c = j / 100, rr = (j % 100) * 4, y = rr / 20, x = rr % 20;
            float* dst = xpad + c * XP + (y + 1) * XS + (x + 1);
            dst[0] = v.x; dst[1] = v.y; dst[2] = v.z; dst[3] = v.w;
        }
    }
    __syncthreads();

    // ---- conv phase: 50 active lanes per wave ----
    const int o0 = 3 * wv;
    if (lane < 50) {
        const int r2 = lane / 5, xc = lane % 5;
        const int y0 = 2 * r2, xq = 4 * xc;
        const int q0 = 10 * r2 + xc;          // quad index of row y0
        const int base = y0 * XS + xq;        // window top-left in padded plane

        float a0[3][4], a1[3][4];
        #pragma unroll
        for (int cc = 0; cc < 3; ++cc) {
            float bo = cb[o0 + cc];           // uniform -> s_load
            #pragma unroll
            for (int sl = 0; sl < 4; ++sl) { a0[cc][sl] = bo; a1[cc][sl] = bo; }
        }

        #pragma unroll
        for (int ci = 0; ci < 6; ++ci) {
            float P[4][6];
            #pragma unroll
            for (int rr = 0; rr < 4; ++rr) {
                const float* rp = xpad + ci * XP + (y0 + rr) * XS + xq;
                #pragma unroll
                for (int t = 0; t < 6; ++t) P[rr][t] = rp[t];
            }
            // wave-uniform weights: 27 SGPR values for this input channel
            float W[3][3][3];
            #pragma unroll
            for (int cc = 0; cc < 3; ++cc)
                #pragma unroll
                for (int ky = 0; ky < 3; ++ky)
                    #pragma unroll
                    for (int tp = 0; tp < 3; ++tp)
                        W[cc][ky][tp] = cw[(o0 + cc) * 54 + ci * 9 + ky * 3 + tp];
            #pragma unroll
            for (int ky = 0; ky < 3; ++ky) {
                #pragma unroll
                for (int cc = 0; cc < 3; ++cc) {
                    float w0 = W[cc][ky][0], w1v = W[cc][ky][1], w2v = W[cc][ky][2];
                    #pragma unroll
                    for (int sl = 0; sl < 4; ++sl) {
                        a0[cc][sl] = fmaf(P[ky][sl], w0,
                                     fmaf(P[ky][sl + 1], w1v,
                                     fmaf(P[ky][sl + 2], w2v, a0[cc][sl])));
                        a1[cc][sl] = fmaf(P[ky + 1][sl], w0,
                                     fmaf(P[ky + 1][sl + 1], w1v,
                                     fmaf(P[ky + 1][sl + 2], w2v, a1[cc][sl])));
                    }
                }
            }
        }
        #pragma unroll
        for (int cc = 0; cc < 3; ++cc) {
            *(float4*)(wl + (o0 + cc) * 404 + 4 * q0) =
                make_float4(a0[cc][0], a0[cc][1], a0[cc][2], a0[cc][3]);
            *(float4*)(wl + (o0 + cc) * 404 + 4 * (q0 + 5)) =
                make_float4(a1[cc][0], a1[cc][1], a1[cc][2], a1[cc][3]);
        }
    }
    __syncthreads();

    // ---- Gram phase: 200 threads x 2 positions (stride-100 scalar reads, conflict-free)
    float g15[15];
    #pragma unroll
    for (int v = 0; v < 15; ++v) g15[v] = 0.f;
    if (tid < 200) {
        #pragma unroll
        for (int pp = 0; pp < 2; ++pp) {
            const int pos = tid + pp * 200;
            #pragma unroll
            for (int cc = 0; cc < 3; ++cc) {
                float ch[5];
                #pragma unroll
                for (int i = 0; i < 5; ++i) ch[i] = wl[(3 * i + cc) * 404 + pos];
                int p = 0;
                #pragma unroll
                for (int i = 0; i < 5; ++i)
                    #pragma unroll
                    for (int j = i; j < 5; ++j, ++p)
                        g15[p] = fmaf(ch[i], ch[j], g15[p]);
            }
        }
    }
    #pragma unroll
    for (int m = 32; m; m >>= 1) {
        #pragma unroll
        for (int v = 0; v < 15; ++v) g15[v] += __shfl_xor(g15[v], m, 64);
    }
    if (lane == 0) {
        #pragma unroll
        for (int v = 0; v < 15; ++v) gred[wv][v] = g15[v];
    }
    __syncthreads();

    // ---- A-matrix (Gram-space modified GS) + combine + coalesced scalar stores ----
    if (tid < 200) {
        float Gm[15];
        #pragma unroll
        for (int v = 0; v < 15; ++v)
            Gm[v] = gred[0][v] + gred[1][v] + gred[2][v] + gred[3][v] + gred[4][v];

        float A[5][5];
        #pragma unroll
        for (int i = 0; i < 5; ++i)
            #pragma unroll
            for (int j = 0; j < 5; ++j) A[i][j] = (i == j) ? 1.f : 0.f;
        #pragma unroll
        for (int j = 0; j < 4; ++j) {
            float v[5];
            #pragma unroll
            for (int r = 0; r < 5; ++r) {
                float s0 = 0.f;
                #pragma unroll
                for (int k = 0; k < 5; ++k)
                    if (k <= j) s0 = fmaf(A[j][k], GF(k, r), s0);
                v[r] = s0;
            }
            float dj = 0.f;
            #pragma unroll
            for (int k = 0; k < 5; ++k)
                if (k <= j) dj = fmaf(A[j][k], v[k], dj);
            float rd = 1.0f / dj;
            #pragma unroll
            for (int i = j + 1; i < 5; ++i) {
                float cij = 0.f;
                #pragma unroll
                for (int k = 0; k < 5; ++k)
                    if (k <= i) cij = fmaf(A[i][k], v[k], cij);
                cij *= rd;
                #pragma unroll
                for (int k = 0; k < 5; ++k)
                    if (k <= j) A[i][k] = fmaf(-cij, A[j][k], A[i][k]);
            }
        }

        float* ob = out + (size_t)b * 6000;
        #pragma unroll
        for (int pp = 0; pp < 2; ++pp) {
            const int pos = tid + pp * 200;
            #pragma unroll
            for (int cc = 0; cc < 3; ++cc) {
                float wq[5];
                #pragma unroll
                for (int k = 0; k < 5; ++k) wq[k] = wl[(3 * k + cc) * 404 + pos];
                #pragma unroll
                for (int d = 4; d >= 0; --d) {
                    float u = wq[d];
                    #pragma unroll
                    for (int k = 0; k < d; ++k) u = fmaf(A[d][k], wq[k], u);
                    ob[(3 * d + cc) * 400 + pos] = u;
                }
            }
        }
    }
}

extern "C" void kernel_launch(void* const* d_in, const int* in_sizes, int n_in,
                              void* d_out, int out_size, void* d_ws, size_t ws_size,
                              hipStream_t stream) {
    const float* x_restored  = (const float*)d_in[0];
    const float* x_distorted = (const float*)d_in[1];
    const float* w1          = (const float*)d_in[2];
    const float* w2          = (const float*)d_in[3];
    const float* b2          = (const float*)d_in[4];
    const float* conv_w      = (const float*)d_in[5];
    const float* conv_b      = (const float*)d_in[6];
    float* out = (float*)d_out;

    float* xd = (float*)d_ws;                                         // 39.3 MB
    unsigned short* hb  = (unsigned short*)(xd + (size_t)NB * 1200);  // 2 MB
    unsigned short* w2b = hb + (size_t)NB * 128;                      // 0.3 MB

    mlp1_kernel<<<(NB * 128) / 256, 256, 0, stream>>>(x_distorted, w1, hb);
    castw2_kernel<<<(1200 * 128) / 256, 256, 0, stream>>>(w2, w2b);
    mlp2_mfma<<<(128 * 25) / 4, 256, 0, stream>>>(hb, w2b, b2, xd);
    conv_gs_kernel<<<NB, 320, 0, stream>>>(xd, x_restored, conv_w, conv_b, out);
}